// Round 4
// baseline (769.273 us; speedup 1.0000x reference)
//
#include <hip/hip_runtime.h>

#define T_TOK 4096
#define DDIM  1024
#define HDIM  2048
#define NEXP  8
#define CAP   13312   // max padded bucket rows: 2T + 8*128-pad + T; worst case exactly 13312

typedef short bf16x8 __attribute__((ext_vector_type(8)));
typedef float f32x4  __attribute__((ext_vector_type(4)));

// ---- workspace layout (bytes) ----
#define WS_XB   ((size_t)0)                                  // T*D bf16
#define WS_HBUF (WS_XB   + (size_t)T_TOK*DDIM*2)             // CAP*H bf16
#define WS_BTOK (WS_HBUF + (size_t)CAP*HDIM*2)               // CAP int
#define WS_BW   (WS_BTOK + (size_t)CAP*4)                    // CAP float
#define WS_IDX  (WS_BW   + (size_t)CAP*4)                    // 2T int
#define WS_WTOP (WS_IDX  + (size_t)2*T_TOK*4)                // 2T float
#define WS_CNT  (WS_WTOP + (size_t)2*T_TOK*4)                // 8 counts + 8 fill
#define WS_OFF  (WS_CNT  + (size_t)64)                       // 10 ints
#define WS_END  (WS_OFF  + (size_t)64)

static __device__ __forceinline__ unsigned short f2bf(float f) {
  unsigned u = __float_as_uint(f);
  unsigned r = (u + 0x7FFFu + ((u >> 16) & 1u)) >> 16;   // RNE, finite inputs
  return (unsigned short)r;
}

// ---------------- sentinel: flag insufficient workspace as a clean absmax failure ----------------
__global__ __launch_bounds__(256) void k_sentinel(float* __restrict__ out) {
  int gid = blockIdx.x * 256 + threadIdx.x;
  int stride = gridDim.x * 256;
  for (int i = gid; i < T_TOK * DDIM; i += stride) out[i] = 1.0e6f;
}

// ---------------- init: zero out, pad-mark buckets, zero counters ----------------
__global__ __launch_bounds__(256) void k_init(float* __restrict__ out,
                                              int* __restrict__ btok,
                                              int* __restrict__ cnt) {
  int gid = blockIdx.x * 256 + threadIdx.x;
  int stride = gridDim.x * 256;
  float4 z = make_float4(0.f, 0.f, 0.f, 0.f);
  for (int i = gid; i < T_TOK * DDIM / 4; i += stride) ((float4*)out)[i] = z;
  for (int i = gid; i < CAP; i += stride) btok[i] = -1;
  if (gid < 16) cnt[gid] = 0;
}

// ---------------- router: logits (fp32), top-2, renorm weights, x -> bf16 ----------------
__global__ __launch_bounds__(256) void k_router(const float* __restrict__ x,
                                                const float* __restrict__ gw,
                                                unsigned short* __restrict__ xb,
                                                int* __restrict__ idx,
                                                float* __restrict__ wtop,
                                                int* __restrict__ counts) {
  int t = blockIdx.x;
  int tid = threadIdx.x;
  float4 xv = ((const float4*)(x + (size_t)t * DDIM))[tid];
  ushort4 xbv = make_ushort4(f2bf(xv.x), f2bf(xv.y), f2bf(xv.z), f2bf(xv.w));
  ((ushort4*)xb)[(size_t)t * (DDIM / 4) + tid] = xbv;

  float p[NEXP];
#pragma unroll
  for (int e = 0; e < NEXP; e++) {
    float4 g = ((const float4*)(gw + (size_t)e * DDIM))[tid];
    p[e] = xv.x * g.x + xv.y * g.y + xv.z * g.z + xv.w * g.w;
  }
#pragma unroll
  for (int e = 0; e < NEXP; e++)
    for (int off = 32; off; off >>= 1) p[e] += __shfl_down(p[e], off, 64);

  __shared__ float red[NEXP][4];
  int lane = tid & 63, wv = tid >> 6;
  if (lane == 0) {
#pragma unroll
    for (int e = 0; e < NEXP; e++) red[e][wv] = p[e];
  }
  __syncthreads();
  if (tid == 0) {
    float l[NEXP];
#pragma unroll
    for (int e = 0; e < NEXP; e++) l[e] = red[e][0] + red[e][1] + red[e][2] + red[e][3];
    int e1 = 0;
#pragma unroll
    for (int e = 1; e < NEXP; e++) if (l[e] > l[e1]) e1 = e;
    int e2 = -1;
#pragma unroll
    for (int e = 0; e < NEXP; e++) {
      if (e == e1) continue;
      if (e2 < 0 || l[e] > l[e2]) e2 = e;
    }
    float p2 = __expf(l[e2] - l[e1]);
    float s = 1.f + p2;
    idx[2 * t] = e1; idx[2 * t + 1] = e2;
    wtop[2 * t] = 1.f / s; wtop[2 * t + 1] = p2 / s;
    atomicAdd(&counts[e1], 1);
    atomicAdd(&counts[e2], 1);
  }
}

// ---------------- offsets: 128-aligned cumsum; shared expert appended as segment 8 ----------------
__global__ void k_offsets(const int* __restrict__ counts, int* __restrict__ off) {
  if (threadIdx.x == 0 && blockIdx.x == 0) {
    int o = 0;
    for (int e = 0; e < NEXP; e++) { off[e] = o; o += ((counts[e] + 127) >> 7) << 7; }
    off[8] = o;
    off[9] = o + T_TOK;
  }
}

// ---------------- scatter tokens into expert buckets ----------------
__global__ __launch_bounds__(256) void k_scatter(const int* __restrict__ idx,
                                                 const float* __restrict__ wtop,
                                                 const int* __restrict__ off,
                                                 int* __restrict__ fill,
                                                 int* __restrict__ btok,
                                                 float* __restrict__ bw) {
  int t = blockIdx.x * 256 + threadIdx.x;
  if (t >= T_TOK) return;
#pragma unroll
  for (int k = 0; k < 2; k++) {
    int e = idx[2 * t + k];
    int pos = atomicAdd(&fill[e], 1);
    int d = off[e] + pos;
    btok[d] = t;
    bw[d] = wtop[2 * t + k];
  }
  int d = off[8] + t;   // shared-expert segment: identity order, weight 1
  btok[d] = t;
  bw[d] = 1.0f;
}

// ---------------- GEMM1: h = silu(x*Wg^T) * (x*Wu^T), grouped over bucket segments ----------------
// tile: 128 rows x 64 h-cols, BK=64, 256 threads (4 waves, 2x2)
__global__ __launch_bounds__(256) void k_swiglu(const unsigned short* __restrict__ xb,
                                                const float* __restrict__ sh_gate,
                                                const float* __restrict__ sh_up,
                                                const float* __restrict__ eg,
                                                const float* __restrict__ eu,
                                                const int* __restrict__ off,
                                                const int* __restrict__ btok,
                                                unsigned short* __restrict__ hbuf) {
  __shared__ unsigned short As[128 * 72];
  __shared__ unsigned short Bg[64 * 72];
  __shared__ unsigned short Bu[64 * 72];

  int row0 = blockIdx.y * 128;
  int offv[10];
#pragma unroll
  for (int q = 0; q < 10; q++) offv[q] = off[q];
  if (row0 >= offv[9]) return;
  int e = 0;
#pragma unroll
  for (int q = 0; q < 9; q++) if (row0 >= offv[q + 1]) e = q + 1;

  const float* bgp;
  const float* bup;
  if (e < NEXP) {
    bgp = eg + (size_t)e * HDIM * DDIM;
    bup = eu + (size_t)e * HDIM * DDIM;
  } else {
    bgp = sh_gate;
    bup = sh_up;
  }
  int n0 = blockIdx.x * 64;
  int tid = threadIdx.x;

  int rtok[4];
#pragma unroll
  for (int j = 0; j < 4; j++) rtok[j] = btok[row0 + j * 32 + (tid >> 3)];

  int wid = tid >> 6, lane = tid & 63;
  int wm = wid >> 1, wn = wid & 1;
  int fr = lane & 15, fq = lane >> 4;

  f32x4 accG[4][2] = {};
  f32x4 accU[4][2] = {};

  for (int kt = 0; kt < DDIM / 64; kt++) {
    // A stage (gathered bf16 rows)
#pragma unroll
    for (int j = 0; j < 4; j++) {
      int r = j * 32 + (tid >> 3), c = tid & 7;
      uint4 v = make_uint4(0, 0, 0, 0);
      if (rtok[j] >= 0)
        v = *(const uint4*)(xb + (size_t)rtok[j] * DDIM + kt * 64 + c * 8);
      *(uint4*)&As[r * 72 + c * 8] = v;
    }
    // B stage (fp32 -> bf16 on the fly), both gate and up
#pragma unroll
    for (int j = 0; j < 4; j++) {
      int q = j * 256 + tid;
      int rb = q >> 4, c = q & 15;
      float4 vg = *(const float4*)(bgp + (size_t)(n0 + rb) * DDIM + kt * 64 + c * 4);
      float4 vu = *(const float4*)(bup + (size_t)(n0 + rb) * DDIM + kt * 64 + c * 4);
      *(ushort4*)&Bg[rb * 72 + c * 4] = make_ushort4(f2bf(vg.x), f2bf(vg.y), f2bf(vg.z), f2bf(vg.w));
      *(ushort4*)&Bu[rb * 72 + c * 4] = make_ushort4(f2bf(vu.x), f2bf(vu.y), f2bf(vu.z), f2bf(vu.w));
    }
    __syncthreads();
#pragma unroll
    for (int ks = 0; ks < 2; ks++) {
      bf16x8 a[4], bgf[2], buf_[2];
#pragma unroll
      for (int i = 0; i < 4; i++)
        a[i] = *(const bf16x8*)&As[(wm * 64 + i * 16 + fr) * 72 + ks * 32 + fq * 8];
#pragma unroll
      for (int j = 0; j < 2; j++) {
        bgf[j]  = *(const bf16x8*)&Bg[(wn * 32 + j * 16 + fr) * 72 + ks * 32 + fq * 8];
        buf_[j] = *(const bf16x8*)&Bu[(wn * 32 + j * 16 + fr) * 72 + ks * 32 + fq * 8];
      }
#pragma unroll
      for (int i = 0; i < 4; i++)
#pragma unroll
        for (int j = 0; j < 2; j++) {
          accG[i][j] = __builtin_amdgcn_mfma_f32_16x16x32_bf16(a[i], bgf[j], accG[i][j], 0, 0, 0);
          accU[i][j] = __builtin_amdgcn_mfma_f32_16x16x32_bf16(a[i], buf_[j], accU[i][j], 0, 0, 0);
        }
    }
    __syncthreads();
  }

  // epilogue: silu(g)*u -> bf16 h (unconditional; pad rows produce 0)
#pragma unroll
  for (int i = 0; i < 4; i++)
#pragma unroll
    for (int j = 0; j < 2; j++)
#pragma unroll
      for (int r = 0; r < 4; r++) {
        float g = accG[i][j][r], u = accU[i][j][r];
        float h = g / (1.f + __expf(-g)) * u;
        int row = row0 + wm * 64 + i * 16 + fq * 4 + r;
        int col = n0 + wn * 32 + j * 16 + fr;
        hbuf[(size_t)row * HDIM + col] = f2bf(h);
      }
}

// ---------------- GEMM2: out[tok] += w * (h * Wd^T), grouped, fp32 atomic ----------------
// tile: 128 rows x 128 d-cols, BK=64, 256 threads (4 waves, 2x2)
__global__ __launch_bounds__(256) void k_down(const unsigned short* __restrict__ hbuf,
                                              const float* __restrict__ sh_down,
                                              const float* __restrict__ ed,
                                              const int* __restrict__ off,
                                              const int* __restrict__ btok,
                                              const float* __restrict__ bw,
                                              float* __restrict__ out) {
  __shared__ unsigned short As[128 * 72];
  __shared__ unsigned short Bs[128 * 72];

  int row0 = blockIdx.y * 128;
  int offv[10];
#pragma unroll
  for (int q = 0; q < 10; q++) offv[q] = off[q];
  if (row0 >= offv[9]) return;
  int e = 0;
#pragma unroll
  for (int q = 0; q < 9; q++) if (row0 >= offv[q + 1]) e = q + 1;

  const float* bd = (e < NEXP) ? (ed + (size_t)e * DDIM * HDIM) : sh_down;
  int n0 = blockIdx.x * 128;
  int tid = threadIdx.x;
  int wid = tid >> 6, lane = tid & 63;
  int wm = wid >> 1, wn = wid & 1;
  int fr = lane & 15, fq = lane >> 4;

  f32x4 acc[4][4] = {};

  for (int kt = 0; kt < HDIM / 64; kt++) {
#pragma unroll
    for (int j = 0; j < 4; j++) {
      int r = j * 32 + (tid >> 3), c = tid & 7;
      *(uint4*)&As[r * 72 + c * 8] =
          *(const uint4*)(hbuf + (size_t)(row0 + r) * HDIM + kt * 64 + c * 8);
    }
#pragma unroll
    for (int j = 0; j < 8; j++) {
      int q = j * 256 + tid;
      int rb = q >> 4, c = q & 15;
      float4 v = *(const float4*)(bd + (size_t)(n0 + rb) * HDIM + kt * 64 + c * 4);
      *(ushort4*)&Bs[rb * 72 + c * 4] = make_ushort4(f2bf(v.x), f2bf(v.y), f2bf(v.z), f2bf(v.w));
    }
    __syncthreads();
#pragma unroll
    for (int ks = 0; ks < 2; ks++) {
      bf16x8 a[4], b[4];
#pragma unroll
      for (int i = 0; i < 4; i++)
        a[i] = *(const bf16x8*)&As[(wm * 64 + i * 16 + fr) * 72 + ks * 32 + fq * 8];
#pragma unroll
      for (int j = 0; j < 4; j++)
        b[j] = *(const bf16x8*)&Bs[(wn * 64 + j * 16 + fr) * 72 + ks * 32 + fq * 8];
#pragma unroll
      for (int i = 0; i < 4; i++)
#pragma unroll
        for (int j = 0; j < 4; j++)
          acc[i][j] = __builtin_amdgcn_mfma_f32_16x16x32_bf16(a[i], b[j], acc[i][j], 0, 0, 0);
    }
    __syncthreads();
  }

#pragma unroll
  for (int i = 0; i < 4; i++)
#pragma unroll
    for (int r = 0; r < 4; r++) {
      int brow = row0 + wm * 64 + i * 16 + fq * 4 + r;
      int tok = btok[brow];
      if (tok < 0) continue;
      float w = bw[brow];
#pragma unroll
      for (int j = 0; j < 4; j++) {
        int col = n0 + wn * 64 + j * 16 + fr;
        atomicAdd(&out[(size_t)tok * DDIM + col], w * acc[i][j][r]);
      }
    }
}

extern "C" void kernel_launch(void* const* d_in, const int* in_sizes, int n_in,
                              void* d_out, int out_size, void* d_ws, size_t ws_size,
                              hipStream_t stream) {
  const float* x       = (const float*)d_in[0];
  const float* gw      = (const float*)d_in[1];
  const float* sh_gate = (const float*)d_in[2];
  const float* sh_up   = (const float*)d_in[3];
  const float* sh_down = (const float*)d_in[4];
  const float* eg      = (const float*)d_in[5];
  const float* eu      = (const float*)d_in[6];
  const float* ed      = (const float*)d_in[7];
  float* out = (float*)d_out;
  char* ws = (char*)d_ws;

  // Guard: if the harness workspace is smaller than our layout, emit a sentinel
  // (clean absmax failure) instead of corrupting memory / crashing the container.
  if (ws_size < WS_END) {
    hipLaunchKernelGGL(k_sentinel, dim3(1024), dim3(256), 0, stream, out);
    return;
  }

  unsigned short* xb   = (unsigned short*)(ws + WS_XB);
  unsigned short* hbuf = (unsigned short*)(ws + WS_HBUF);
  int*   btok  = (int*)(ws + WS_BTOK);
  float* bw    = (float*)(ws + WS_BW);
  int*   idx   = (int*)(ws + WS_IDX);
  float* wtop  = (float*)(ws + WS_WTOP);
  int*   cnt   = (int*)(ws + WS_CNT);
  int*   fill  = cnt + 8;
  int*   off   = (int*)(ws + WS_OFF);

  hipLaunchKernelGGL(k_init,    dim3(2048), dim3(256), 0, stream, out, btok, cnt);
  hipLaunchKernelGGL(k_router,  dim3(T_TOK), dim3(256), 0, stream, x, gw, xb, idx, wtop, cnt);
  hipLaunchKernelGGL(k_offsets, dim3(1), dim3(64), 0, stream, cnt, off);
  hipLaunchKernelGGL(k_scatter, dim3(T_TOK / 256), dim3(256), 0, stream, idx, wtop, off, fill, btok, bw);
  hipLaunchKernelGGL(k_swiglu,  dim3(HDIM / 64, CAP / 128), dim3(256), 0, stream,
                     xb, sh_gate, sh_up, eg, eu, off, btok, hbuf);
  hipLaunchKernelGGL(k_down,    dim3(DDIM / 128, CAP / 128), dim3(256), 0, stream,
                     hbuf, sh_down, ed, off, btok, bw, out);
}

// Round 7
// 680.542 us; speedup vs baseline: 1.1304x; 1.1304x over previous
//
#include <hip/hip_runtime.h>

#define T_TOK 4096
#define DDIM  1024
#define HDIM  2048
#define NEXP  8
#define CAP   13312   // max padded bucket rows: 2T + 8*128-pad + T; worst case exactly 13312

typedef short bf16x8 __attribute__((ext_vector_type(8)));
typedef float f32x4  __attribute__((ext_vector_type(4)));

// ---- small (fallback) workspace layout (bytes) ----
#define WS_XB   ((size_t)0)
#define WS_HBUF (WS_XB   + (size_t)T_TOK*DDIM*2)
#define WS_BTOK (WS_HBUF + (size_t)CAP*HDIM*2)
#define WS_BW   (WS_BTOK + (size_t)CAP*4)
#define WS_IDX  (WS_BW   + (size_t)CAP*4)
#define WS_WTOP (WS_IDX  + (size_t)2*T_TOK*4)
#define WS_CNT  (WS_WTOP + (size_t)2*T_TOK*4)
#define WS_OFF  (WS_CNT  + (size_t)64)
#define WS_END  (WS_OFF  + (size_t)64)

// ---- big workspace layout: + bf16 weight copies + zero row ----
#define NEW_EXP ((size_t)NEXP*HDIM*DDIM)     // 16,777,216 elems per expert array
#define NSH     ((size_t)HDIM*DDIM)          // 2,097,152 elems per shared array
#define WS2_XB   ((size_t)0)
#define WS2_HBUF (WS2_XB   + (size_t)T_TOK*DDIM*2)
#define WS2_EGB  (WS2_HBUF + (size_t)CAP*HDIM*2)
#define WS2_EUB  (WS2_EGB  + NEW_EXP*2)
#define WS2_EDB  (WS2_EUB  + NEW_EXP*2)
#define WS2_SGB  (WS2_EDB  + NEW_EXP*2)
#define WS2_SUB  (WS2_SGB  + NSH*2)
#define WS2_SDB  (WS2_SUB  + NSH*2)
#define WS2_BTOK (WS2_SDB  + NSH*2)
#define WS2_BW   (WS2_BTOK + (size_t)CAP*4)
#define WS2_IDX  (WS2_BW   + (size_t)CAP*4)
#define WS2_WTOP (WS2_IDX  + (size_t)2*T_TOK*4)
#define WS2_CNT  (WS2_WTOP + (size_t)2*T_TOK*4)
#define WS2_OFF  (WS2_CNT  + (size_t)64)
#define WS2_ZROW (WS2_OFF  + (size_t)64)
#define WS2_END  (WS2_ZROW + (size_t)4096)

static __device__ __forceinline__ unsigned short f2bf(float f) {
  unsigned u = __float_as_uint(f);
  unsigned r = (u + 0x7FFFu + ((u >> 16) & 1u)) >> 16;   // RNE, finite inputs
  return (unsigned short)r;
}

static __device__ __forceinline__ void gll16(const void* g, void* l) {
  __builtin_amdgcn_global_load_lds((const __attribute__((address_space(1))) void*)g,
                                   (__attribute__((address_space(3))) void*)l, 16, 0, 0);
}

// ---------------- sentinel: flag insufficient workspace as a clean absmax failure ----------------
__global__ __launch_bounds__(256) void k_sentinel(float* __restrict__ out) {
  int gid = blockIdx.x * 256 + threadIdx.x;
  int stride = gridDim.x * 256;
  for (int i = gid; i < T_TOK * DDIM; i += stride) out[i] = 1.0e6f;
}

// ---------------- init: zero out, pad-mark buckets, zero counters + zero-row ----------------
__global__ __launch_bounds__(256) void k_init(float* __restrict__ out,
                                              int* __restrict__ btok,
                                              int* __restrict__ cnt,
                                              unsigned int* __restrict__ zz) {
  int gid = blockIdx.x * 256 + threadIdx.x;
  int stride = gridDim.x * 256;
  float4 z = make_float4(0.f, 0.f, 0.f, 0.f);
  for (int i = gid; i < T_TOK * DDIM / 4; i += stride) ((float4*)out)[i] = z;
  for (int i = gid; i < CAP; i += stride) btok[i] = -1;
  for (int i = gid; i < 1024; i += stride) zz[i] = 0u;
  if (gid < 16) cnt[gid] = 0;
}

// ---------------- weight fp32 -> bf16 pre-conversion (big path) ----------------
#define NE8 ((long)(NEW_EXP / 8))   // 2^21
#define NS8 ((long)(NSH / 8))       // 2^18
__global__ __launch_bounds__(256) void k_convert(
    const float* __restrict__ eg, const float* __restrict__ eu, const float* __restrict__ ed,
    const float* __restrict__ sg, const float* __restrict__ su, const float* __restrict__ sd,
    unsigned short* __restrict__ egb, unsigned short* __restrict__ eub, unsigned short* __restrict__ edb,
    unsigned short* __restrict__ sgb, unsigned short* __restrict__ sub, unsigned short* __restrict__ sdb) {
  long gid = (long)blockIdx.x * 256 + threadIdx.x;
  long stride = (long)gridDim.x * 256;
  const long TOT8 = 3 * NE8 + 3 * NS8;
  for (long i = gid; i < TOT8; i += stride) {
    const float* s; unsigned short* d; long o;
    if (i < 3 * NE8) {
      long a = i >> 21, r = i & (NE8 - 1);
      s = (a == 0) ? eg : ((a == 1) ? eu : ed);
      d = (a == 0) ? egb : ((a == 1) ? eub : edb);
      o = r;
    } else {
      long b = i - 3 * NE8;
      long a = b >> 18, r = b & (NS8 - 1);
      s = (a == 0) ? sg : ((a == 1) ? su : sd);
      d = (a == 0) ? sgb : ((a == 1) ? sub : sdb);
      o = r;
    }
    float4 v0 = ((const float4*)s)[o * 2];
    float4 v1 = ((const float4*)s)[o * 2 + 1];
    ((ushort4*)d)[o * 2]     = make_ushort4(f2bf(v0.x), f2bf(v0.y), f2bf(v0.z), f2bf(v0.w));
    ((ushort4*)d)[o * 2 + 1] = make_ushort4(f2bf(v1.x), f2bf(v1.y), f2bf(v1.z), f2bf(v1.w));
  }
}

// ---------------- router: logits (fp32), top-2, renorm weights, x -> bf16 ----------------
__global__ __launch_bounds__(256) void k_router(const float* __restrict__ x,
                                                const float* __restrict__ gw,
                                                unsigned short* __restrict__ xb,
                                                int* __restrict__ idx,
                                                float* __restrict__ wtop,
                                                int* __restrict__ counts) {
  int t = blockIdx.x;
  int tid = threadIdx.x;
  float4 xv = ((const float4*)(x + (size_t)t * DDIM))[tid];
  ushort4 xbv = make_ushort4(f2bf(xv.x), f2bf(xv.y), f2bf(xv.z), f2bf(xv.w));
  ((ushort4*)xb)[(size_t)t * (DDIM / 4) + tid] = xbv;

  float p[NEXP];
#pragma unroll
  for (int e = 0; e < NEXP; e++) {
    float4 g = ((const float4*)(gw + (size_t)e * DDIM))[tid];
    p[e] = xv.x * g.x + xv.y * g.y + xv.z * g.z + xv.w * g.w;
  }
#pragma unroll
  for (int e = 0; e < NEXP; e++)
    for (int off = 32; off; off >>= 1) p[e] += __shfl_down(p[e], off, 64);

  __shared__ float red[NEXP][4];
  int lane = tid & 63, wv = tid >> 6;
  if (lane == 0) {
#pragma unroll
    for (int e = 0; e < NEXP; e++) red[e][wv] = p[e];
  }
  __syncthreads();
  if (tid == 0) {
    float l[NEXP];
#pragma unroll
    for (int e = 0; e < NEXP; e++) l[e] = red[e][0] + red[e][1] + red[e][2] + red[e][3];
    int e1 = 0;
#pragma unroll
    for (int e = 1; e < NEXP; e++) if (l[e] > l[e1]) e1 = e;
    int e2 = -1;
#pragma unroll
    for (int e = 0; e < NEXP; e++) {
      if (e == e1) continue;
      if (e2 < 0 || l[e] > l[e2]) e2 = e;
    }
    float p2 = __expf(l[e2] - l[e1]);
    float s = 1.f + p2;
    idx[2 * t] = e1; idx[2 * t + 1] = e2;
    wtop[2 * t] = 1.f / s; wtop[2 * t + 1] = p2 / s;
    atomicAdd(&counts[e1], 1);
    atomicAdd(&counts[e2], 1);
  }
}

// ---------------- offsets: 128-aligned cumsum; shared expert appended as segment 8 ----------------
__global__ void k_offsets(const int* __restrict__ counts, int* __restrict__ off) {
  if (threadIdx.x == 0 && blockIdx.x == 0) {
    int o = 0;
    for (int e = 0; e < NEXP; e++) { off[e] = o; o += ((counts[e] + 127) >> 7) << 7; }
    off[8] = o;
    off[9] = o + T_TOK;
  }
}

// ---------------- scatter tokens into expert buckets ----------------
__global__ __launch_bounds__(256) void k_scatter(const int* __restrict__ idx,
                                                 const float* __restrict__ wtop,
                                                 const int* __restrict__ off,
                                                 int* __restrict__ fill,
                                                 int* __restrict__ btok,
                                                 float* __restrict__ bw) {
  int t = blockIdx.x * 256 + threadIdx.x;
  if (t >= T_TOK) return;
#pragma unroll
  for (int k = 0; k < 2; k++) {
    int e = idx[2 * t + k];
    int pos = atomicAdd(&fill[e], 1);
    int d = off[e] + pos;
    btok[d] = t;
    bw[d] = wtop[2 * t + k];
  }
  int d = off[8] + t;   // shared-expert segment: identity order, weight 1
  btok[d] = t;
  bw[d] = 1.0f;
}

// ============================================================================
// BIG PATH GEMMs: bf16 weights, global_load_lds width-16, XOR-swizzled LDS.
// Swizzle contract (rule #21): LDS linear [rows][64] shorts (128B rows, 8
// chunks of 16B). Physical chunk p of row r holds global chunk c = p^(r&7).
// Write: lane l of a 1KB section (8 rows) has p=l&7, r_lo=l>>3 -> loads
// global chunk (l&7)^(l>>3). Read: chunk k of row r is at physical k^(r&7).
// ============================================================================

// ---------------- GEMM1 (big): h = silu(x*Wg^T)*(x*Wu^T) ----------------
// tile 128 rows x 64 h-cols (gate+up), BK=64, 256 thr (4 waves, 2x2)
__global__ __launch_bounds__(256) void k_swiglu2(const unsigned short* __restrict__ xb,
                                                 const unsigned short* __restrict__ sgb,
                                                 const unsigned short* __restrict__ sub,
                                                 const unsigned short* __restrict__ egb,
                                                 const unsigned short* __restrict__ eub,
                                                 const int* __restrict__ off,
                                                 const int* __restrict__ btok,
                                                 const unsigned short* __restrict__ zrow,
                                                 unsigned short* __restrict__ hbuf) {
  __shared__ __align__(16) unsigned short As[128 * 64];
  __shared__ __align__(16) unsigned short Bg[64 * 64];
  __shared__ __align__(16) unsigned short Bu[64 * 64];

  int row0 = blockIdx.y * 128;
  int offv[10];
#pragma unroll
  for (int q = 0; q < 10; q++) offv[q] = off[q];
  if (row0 >= offv[9]) return;
  int e = 0;
#pragma unroll
  for (int q = 0; q < 9; q++) if (row0 >= offv[q + 1]) e = q + 1;

  const unsigned short* bgp = (e < NEXP) ? (egb + (size_t)e * HDIM * DDIM) : sgb;
  const unsigned short* bup = (e < NEXP) ? (eub + (size_t)e * HDIM * DDIM) : sub;
  int n0 = blockIdx.x * 64;
  int tid = threadIdx.x;
  int w = tid >> 6, l = tid & 63;
  int lr = l >> 3;              // row-in-section
  int c  = (l & 7) ^ lr;        // inverse-swizzled global chunk (x8 shorts)

  // per-lane global source bases (chunk offset folded in)
  const unsigned short* asrc[4];
#pragma unroll
  for (int j = 0; j < 4; j++) {
    int tok = btok[row0 + w * 32 + j * 8 + lr];
    asrc[j] = ((tok >= 0) ? (xb + (size_t)tok * DDIM) : zrow) + c * 8;
  }
  const unsigned short* bgsrc[2];
  const unsigned short* busrc[2];
#pragma unroll
  for (int j = 0; j < 2; j++) {
    int rb = w * 16 + j * 8 + lr;
    bgsrc[j] = bgp + (size_t)(n0 + rb) * DDIM + c * 8;
    busrc[j] = bup + (size_t)(n0 + rb) * DDIM + c * 8;
  }

  int wm = w >> 1, wn = w & 1;
  int fr = l & 15, fq = l >> 4;
  int f7 = fr & 7;

  f32x4 accG[4][2] = {};
  f32x4 accU[4][2] = {};

  for (int kt = 0; kt < DDIM / 64; kt++) {
    int ko = kt * 64;
#pragma unroll
    for (int j = 0; j < 4; j++)
      gll16(asrc[j] + ko, As + (w * 32 + j * 8) * 64);
#pragma unroll
    for (int j = 0; j < 2; j++) {
      gll16(bgsrc[j] + ko, Bg + (w * 16 + j * 8) * 64);
      gll16(busrc[j] + ko, Bu + (w * 16 + j * 8) * 64);
    }
    __syncthreads();   // drains vmcnt(0): LDS tiles complete
#pragma unroll
    for (int ks = 0; ks < 2; ks++) {
      int ck = ks * 4 + fq;
      bf16x8 a[4], bgf[2], buf_[2];
#pragma unroll
      for (int i = 0; i < 4; i++)
        a[i] = *(const bf16x8*)&As[(wm * 64 + i * 16 + fr) * 64 + ((ck ^ f7) * 8)];
#pragma unroll
      for (int j = 0; j < 2; j++) {
        bgf[j]  = *(const bf16x8*)&Bg[(wn * 32 + j * 16 + fr) * 64 + ((ck ^ f7) * 8)];
        buf_[j] = *(const bf16x8*)&Bu[(wn * 32 + j * 16 + fr) * 64 + ((ck ^ f7) * 8)];
      }
#pragma unroll
      for (int i = 0; i < 4; i++)
#pragma unroll
        for (int j = 0; j < 2; j++) {
          accG[i][j] = __builtin_amdgcn_mfma_f32_16x16x32_bf16(a[i], bgf[j], accG[i][j], 0, 0, 0);
          accU[i][j] = __builtin_amdgcn_mfma_f32_16x16x32_bf16(a[i], buf_[j], accU[i][j], 0, 0, 0);
        }
    }
    __syncthreads();   // all waves done reading before next overwrite
  }

#pragma unroll
  for (int i = 0; i < 4; i++)
#pragma unroll
    for (int j = 0; j < 2; j++)
#pragma unroll
      for (int r = 0; r < 4; r++) {
        float g = accG[i][j][r], u = accU[i][j][r];
        float h = g / (1.f + __expf(-g)) * u;
        int row = row0 + wm * 64 + i * 16 + fq * 4 + r;
        int col = n0 + wn * 32 + j * 16 + fr;
        hbuf[(size_t)row * HDIM + col] = f2bf(h);
      }
}

// ---------------- GEMM2 (big): out[tok] += w * (h * Wd^T) ----------------
// tile 128 rows x 128 d-cols, BK=64, 256 thr (4 waves, 2x2)
__global__ __launch_bounds__(256) void k_down2(const unsigned short* __restrict__ hbuf,
                                               const unsigned short* __restrict__ sdb,
                                               const unsigned short* __restrict__ edb,
                                               const int* __restrict__ off,
                                               const int* __restrict__ btok,
                                               const float* __restrict__ bw,
                                               float* __restrict__ out) {
  __shared__ __align__(16) unsigned short As[128 * 64];
  __shared__ __align__(16) unsigned short Bs[128 * 64];

  int row0 = blockIdx.y * 128;
  int offv[10];
#pragma unroll
  for (int q = 0; q < 10; q++) offv[q] = off[q];
  if (row0 >= offv[9]) return;
  int e = 0;
#pragma unroll
  for (int q = 0; q < 9; q++) if (row0 >= offv[q + 1]) e = q + 1;

  const unsigned short* bd = (e < NEXP) ? (edb + (size_t)e * DDIM * HDIM) : sdb;
  int n0 = blockIdx.x * 128;
  int tid = threadIdx.x;
  int w = tid >> 6, l = tid & 63;
  int lr = l >> 3;
  int c  = (l & 7) ^ lr;

  const unsigned short* asrc[4];
  const unsigned short* bsrc[4];
#pragma unroll
  for (int j = 0; j < 4; j++) {
    int r = (w * 4 + j) * 8 + lr;
    asrc[j] = hbuf + (size_t)(row0 + r) * HDIM + c * 8;
    bsrc[j] = bd   + (size_t)(n0 + r) * HDIM + c * 8;
  }

  int wm = w >> 1, wn = w & 1;
  int fr = l & 15, fq = l >> 4;
  int f7 = fr & 7;

  f32x4 acc[4][4] = {};

  for (int kt = 0; kt < HDIM / 64; kt++) {
    int ko = kt * 64;
#pragma unroll
    for (int j = 0; j < 4; j++) {
      gll16(asrc[j] + ko, As + (w * 4 + j) * 8 * 64);
      gll16(bsrc[j] + ko, Bs + (w * 4 + j) * 8 * 64);
    }
    __syncthreads();
#pragma unroll
    for (int ks = 0; ks < 2; ks++) {
      int ck = ks * 4 + fq;
      bf16x8 a[4], b[4];
#pragma unroll
      for (int i = 0; i < 4; i++)
        a[i] = *(const bf16x8*)&As[(wm * 64 + i * 16 + fr) * 64 + ((ck ^ f7) * 8)];
#pragma unroll
      for (int j = 0; j < 4; j++)
        b[j] = *(const bf16x8*)&Bs[(wn * 64 + j * 16 + fr) * 64 + ((ck ^ f7) * 8)];
#pragma unroll
      for (int i = 0; i < 4; i++)
#pragma unroll
        for (int j = 0; j < 4; j++)
          acc[i][j] = __builtin_amdgcn_mfma_f32_16x16x32_bf16(a[i], b[j], acc[i][j], 0, 0, 0);
    }
    __syncthreads();
  }

#pragma unroll
  for (int i = 0; i < 4; i++)
#pragma unroll
    for (int r = 0; r < 4; r++) {
      int brow = row0 + wm * 64 + i * 16 + fq * 4 + r;
      int tok = btok[brow];
      if (tok < 0) continue;
      float wgt = bw[brow];
#pragma unroll
      for (int j = 0; j < 4; j++) {
        int col = n0 + wn * 64 + j * 16 + fr;
        atomicAdd(&out[(size_t)tok * DDIM + col], wgt * acc[i][j][r]);
      }
    }
}

// ============================================================================
// FALLBACK PATH GEMMs (round-3/4 proven): fp32 weights converted in-flight.
// ============================================================================
__global__ __launch_bounds__(256) void k_swiglu(const unsigned short* __restrict__ xb,
                                                const float* __restrict__ sh_gate,
                                                const float* __restrict__ sh_up,
                                                const float* __restrict__ eg,
                                                const float* __restrict__ eu,
                                                const int* __restrict__ off,
                                                const int* __restrict__ btok,
                                                unsigned short* __restrict__ hbuf) {
  __shared__ unsigned short As[128 * 72];
  __shared__ unsigned short Bg[64 * 72];
  __shared__ unsigned short Bu[64 * 72];

  int row0 = blockIdx.y * 128;
  int offv[10];
#pragma unroll
  for (int q = 0; q < 10; q++) offv[q] = off[q];
  if (row0 >= offv[9]) return;
  int e = 0;
#pragma unroll
  for (int q = 0; q < 9; q++) if (row0 >= offv[q + 1]) e = q + 1;

  const float* bgp;
  const float* bup;
  if (e < NEXP) {
    bgp = eg + (size_t)e * HDIM * DDIM;
    bup = eu + (size_t)e * HDIM * DDIM;
  } else {
    bgp = sh_gate;
    bup = sh_up;
  }
  int n0 = blockIdx.x * 64;
  int tid = threadIdx.x;

  int rtok[4];
#pragma unroll
  for (int j = 0; j < 4; j++) rtok[j] = btok[row0 + j * 32 + (tid >> 3)];

  int wid = tid >> 6, lane = tid & 63;
  int wm = wid >> 1, wn = wid & 1;
  int fr = lane & 15, fq = lane >> 4;

  f32x4 accG[4][2] = {};
  f32x4 accU[4][2] = {};

  for (int kt = 0; kt < DDIM / 64; kt++) {
#pragma unroll
    for (int j = 0; j < 4; j++) {
      int r = j * 32 + (tid >> 3), cc = tid & 7;
      uint4 v = make_uint4(0, 0, 0, 0);
      if (rtok[j] >= 0)
        v = *(const uint4*)(xb + (size_t)rtok[j] * DDIM + kt * 64 + cc * 8);
      *(uint4*)&As[r * 72 + cc * 8] = v;
    }
#pragma unroll
    for (int j = 0; j < 4; j++) {
      int q = j * 256 + tid;
      int rb = q >> 4, cc = q & 15;
      float4 vg = *(const float4*)(bgp + (size_t)(n0 + rb) * DDIM + kt * 64 + cc * 4);
      float4 vu = *(const float4*)(bup + (size_t)(n0 + rb) * DDIM + kt * 64 + cc * 4);
      *(ushort4*)&Bg[rb * 72 + cc * 4] = make_ushort4(f2bf(vg.x), f2bf(vg.y), f2bf(vg.z), f2bf(vg.w));
      *(ushort4*)&Bu[rb * 72 + cc * 4] = make_ushort4(f2bf(vu.x), f2bf(vu.y), f2bf(vu.z), f2bf(vu.w));
    }
    __syncthreads();
#pragma unroll
    for (int ks = 0; ks < 2; ks++) {
      bf16x8 a[4], bgf[2], buf_[2];
#pragma unroll
      for (int i = 0; i < 4; i++)
        a[i] = *(const bf16x8*)&As[(wm * 64 + i * 16 + fr) * 72 + ks * 32 + fq * 8];
#pragma unroll
      for (int j = 0; j < 2; j++) {
        bgf[j]  = *(const bf16x8*)&Bg[(wn * 32 + j * 16 + fr) * 72 + ks * 32 + fq * 8];
        buf_[j] = *(const bf16x8*)&Bu[(wn * 32 + j * 16 + fr) * 72 + ks * 32 + fq * 8];
      }
#pragma unroll
      for (int i = 0; i < 4; i++)
#pragma unroll
        for (int j = 0; j < 2; j++) {
          accG[i][j] = __builtin_amdgcn_mfma_f32_16x16x32_bf16(a[i], bgf[j], accG[i][j], 0, 0, 0);
          accU[i][j] = __builtin_amdgcn_mfma_f32_16x16x32_bf16(a[i], buf_[j], accU[i][j], 0, 0, 0);
        }
    }
    __syncthreads();
  }

#pragma unroll
  for (int i = 0; i < 4; i++)
#pragma unroll
    for (int j = 0; j < 2; j++)
#pragma unroll
      for (int r = 0; r < 4; r++) {
        float g = accG[i][j][r], u = accU[i][j][r];
        float h = g / (1.f + __expf(-g)) * u;
        int row = row0 + wm * 64 + i * 16 + fq * 4 + r;
        int col = n0 + wn * 32 + j * 16 + fr;
        hbuf[(size_t)row * HDIM + col] = f2bf(h);
      }
}

__global__ __launch_bounds__(256) void k_down(const unsigned short* __restrict__ hbuf,
                                              const float* __restrict__ sh_down,
                                              const float* __restrict__ ed,
                                              const int* __restrict__ off,
                                              const int* __restrict__ btok,
                                              const float* __restrict__ bw,
                                              float* __restrict__ out) {
  __shared__ unsigned short As[128 * 72];
  __shared__ unsigned short Bs[128 * 72];

  int row0 = blockIdx.y * 128;
  int offv[10];
#pragma unroll
  for (int q = 0; q < 10; q++) offv[q] = off[q];
  if (row0 >= offv[9]) return;
  int e = 0;
#pragma unroll
  for (int q = 0; q < 9; q++) if (row0 >= offv[q + 1]) e = q + 1;

  const float* bd = (e < NEXP) ? (ed + (size_t)e * DDIM * HDIM) : sh_down;
  int n0 = blockIdx.x * 128;
  int tid = threadIdx.x;
  int wid = tid >> 6, lane = tid & 63;
  int wm = wid >> 1, wn = wid & 1;
  int fr = lane & 15, fq = lane >> 4;

  f32x4 acc[4][4] = {};

  for (int kt = 0; kt < HDIM / 64; kt++) {
#pragma unroll
    for (int j = 0; j < 4; j++) {
      int r = j * 32 + (tid >> 3), cc = tid & 7;
      *(uint4*)&As[r * 72 + cc * 8] =
          *(const uint4*)(hbuf + (size_t)(row0 + r) * HDIM + kt * 64 + cc * 8);
    }
#pragma unroll
    for (int j = 0; j < 8; j++) {
      int q = j * 256 + tid;
      int rb = q >> 4, cc = q & 15;
      float4 v = *(const float4*)(bd + (size_t)(n0 + rb) * HDIM + kt * 64 + cc * 4);
      *(ushort4*)&Bs[rb * 72 + cc * 4] = make_ushort4(f2bf(v.x), f2bf(v.y), f2bf(v.z), f2bf(v.w));
    }
    __syncthreads();
#pragma unroll
    for (int ks = 0; ks < 2; ks++) {
      bf16x8 a[4], b[4];
#pragma unroll
      for (int i = 0; i < 4; i++)
        a[i] = *(const bf16x8*)&As[(wm * 64 + i * 16 + fr) * 72 + ks * 32 + fq * 8];
#pragma unroll
      for (int j = 0; j < 4; j++)
        b[j] = *(const bf16x8*)&Bs[(wn * 64 + j * 16 + fr) * 72 + ks * 32 + fq * 8];
#pragma unroll
      for (int i = 0; i < 4; i++)
#pragma unroll
        for (int j = 0; j < 4; j++)
          acc[i][j] = __builtin_amdgcn_mfma_f32_16x16x32_bf16(a[i], b[j], acc[i][j], 0, 0, 0);
    }
    __syncthreads();
  }

#pragma unroll
  for (int i = 0; i < 4; i++)
#pragma unroll
    for (int r = 0; r < 4; r++) {
      int brow = row0 + wm * 64 + i * 16 + fq * 4 + r;
      int tok = btok[brow];
      if (tok < 0) continue;
      float w = bw[brow];
#pragma unroll
      for (int j = 0; j < 4; j++) {
        int col = n0 + wn * 64 + j * 16 + fr;
        atomicAdd(&out[(size_t)tok * DDIM + col], w * acc[i][j][r]);
      }
    }
}

extern "C" void kernel_launch(void* const* d_in, const int* in_sizes, int n_in,
                              void* d_out, int out_size, void* d_ws, size_t ws_size,
                              hipStream_t stream) {
  const float* x       = (const float*)d_in[0];
  const float* gw      = (const float*)d_in[1];
  const float* sh_gate = (const float*)d_in[2];
  const float* sh_up   = (const float*)d_in[3];
  const float* sh_down = (const float*)d_in[4];
  const float* eg      = (const float*)d_in[5];
  const float* eu      = (const float*)d_in[6];
  const float* ed      = (const float*)d_in[7];
  float* out = (float*)d_out;
  char* ws = (char*)d_ws;

  if (ws_size >= WS2_END) {
    // ---- big path: bf16 weights + global_load_lds GEMMs ----
    unsigned short* xb   = (unsigned short*)(ws + WS2_XB);
    unsigned short* hbuf = (unsigned short*)(ws + WS2_HBUF);
    unsigned short* egb  = (unsigned short*)(ws + WS2_EGB);
    unsigned short* eub  = (unsigned short*)(ws + WS2_EUB);
    unsigned short* edb  = (unsigned short*)(ws + WS2_EDB);
    unsigned short* sgb  = (unsigned short*)(ws + WS2_SGB);
    unsigned short* sub  = (unsigned short*)(ws + WS2_SUB);
    unsigned short* sdb  = (unsigned short*)(ws + WS2_SDB);
    int*   btok  = (int*)(ws + WS2_BTOK);
    float* bw    = (float*)(ws + WS2_BW);
    int*   idx   = (int*)(ws + WS2_IDX);
    float* wtop  = (float*)(ws + WS2_WTOP);
    int*   cnt   = (int*)(ws + WS2_CNT);
    int*   fill  = cnt + 8;
    int*   off   = (int*)(ws + WS2_OFF);
    unsigned short* zrow = (unsigned short*)(ws + WS2_ZROW);

    hipLaunchKernelGGL(k_init,    dim3(2048), dim3(256), 0, stream, out, btok, cnt, (unsigned int*)zrow);
    hipLaunchKernelGGL(k_convert, dim3(2048), dim3(256), 0, stream,
                       eg, eu, ed, sh_gate, sh_up, sh_down, egb, eub, edb, sgb, sub, sdb);
    hipLaunchKernelGGL(k_router,  dim3(T_TOK), dim3(256), 0, stream, x, gw, xb, idx, wtop, cnt);
    hipLaunchKernelGGL(k_offsets, dim3(1), dim3(64), 0, stream, cnt, off);
    hipLaunchKernelGGL(k_scatter, dim3(T_TOK / 256), dim3(256), 0, stream, idx, wtop, off, fill, btok, bw);
    hipLaunchKernelGGL(k_swiglu2, dim3(HDIM / 64, CAP / 128), dim3(256), 0, stream,
                       xb, sgb, sub, egb, eub, off, btok, zrow, hbuf);
    hipLaunchKernelGGL(k_down2,   dim3(DDIM / 128, CAP / 128), dim3(256), 0, stream,
                       hbuf, sdb, edb, off, btok, bw, out);
  } else if (ws_size >= WS_END) {
    // ---- fallback: round-3 proven path ----
    unsigned short* xb   = (unsigned short*)(ws + WS_XB);
    unsigned short* hbuf = (unsigned short*)(ws + WS_HBUF);
    int*   btok  = (int*)(ws + WS_BTOK);
    float* bw    = (float*)(ws + WS_BW);
    int*   idx   = (int*)(ws + WS_IDX);
    float* wtop  = (float*)(ws + WS_WTOP);
    int*   cnt   = (int*)(ws + WS_CNT);
    int*   fill  = cnt + 8;
    int*   off   = (int*)(ws + WS_OFF);

    hipLaunchKernelGGL(k_init,    dim3(2048), dim3(256), 0, stream, out, btok, cnt, (unsigned int*)xb);
    hipLaunchKernelGGL(k_router,  dim3(T_TOK), dim3(256), 0, stream, x, gw, xb, idx, wtop, cnt);
    hipLaunchKernelGGL(k_offsets, dim3(1), dim3(64), 0, stream, cnt, off);
    hipLaunchKernelGGL(k_scatter, dim3(T_TOK / 256), dim3(256), 0, stream, idx, wtop, off, fill, btok, bw);
    hipLaunchKernelGGL(k_swiglu,  dim3(HDIM / 64, CAP / 128), dim3(256), 0, stream,
                       xb, sh_gate, sh_up, eg, eu, off, btok, hbuf);
    hipLaunchKernelGGL(k_down,    dim3(DDIM / 128, CAP / 128), dim3(256), 0, stream,
                       hbuf, sh_down, ed, off, btok, bw, out);
  } else {
    hipLaunchKernelGGL(k_sentinel, dim3(1024), dim3(256), 0, stream, out);
  }
}